// Round 8
// baseline (1136.365 us; speedup 1.0000x reference)
//
#include <hip/hip_runtime.h>
#include <math.h>

typedef __bf16 bf16_t;
typedef __bf16 bf16x8 __attribute__((ext_vector_type(8)));
typedef float  f32x4  __attribute__((ext_vector_type(4)));

__device__ __forceinline__ void gl2lds16(const void* g, void* l) {
  __builtin_amdgcn_global_load_lds((__attribute__((address_space(1))) void*)g,
                                   (__attribute__((address_space(3))) void*)l,
                                   16, 0, 0);
}

#define MFMA16(a, b, c) __builtin_amdgcn_mfma_f32_16x16x32_bf16(a, b, c, 0, 0, 0)

// ---------------------------------------------------------------------------
// 256x256 tile, BK=32, 8 waves (2M x 4N), 4 LDS buffers x 32 KiB, pipeline
// depth 3 with COUNTED vmcnt gates (T4 -- the lever m218 shows is the entire
// 8-phase gain; every prior round drained vmcnt(0) per tile = documented
// "8-phase-with-drain0 == 1-phase" failure).
// Steady state per tile t:
//   vmcnt(8): waits ONLY tile t's 4 loads (issued 3 tiles earlier, ~free);
//             t+1/t+2's 8 loads remain in flight ACROSS the barrier.
//   s_barrier (all waves gated their own loads -> buffer fully written)
//   stage(t+3) into buf (t+3)&3 == buf (t-1)&3, freed at this barrier
//   12 ds_read_b128 + setprio(1) 32 MFMA setprio(0)
// Tail: phantom wrap-staging keeps vmcnt population uniform (loads valid,
// data unused, written to dead buffers).
// Swizzle (64B rows): LDS granule g holds global granule g^(row&3); staging
// pre-swizzles the GLOBAL source (LDS dest linear, m104 rule); reads XOR.
// T1 bijective XCD swizzle, n-major chunks (B-panels L2-hot per XCD).
// C = A * B^T. MODE 0: fused QKV epilogue (seg = n0>>11: 0->q=sigmoid,
// 1->k=sigmoid(-v) + g=logsigmoid(v), 2->v). MODE 1: f32 passthrough out.
// ---------------------------------------------------------------------------
template<int MODE>
__global__ __launch_bounds__(512, 1)
void gemm256(const bf16_t* __restrict__ A, const bf16_t* __restrict__ Bw,
             bf16_t* __restrict__ oq, bf16_t* __restrict__ okk,
             bf16_t* __restrict__ ov, float* __restrict__ og,
             float* __restrict__ of, int M, int N, int K)
{
  extern __shared__ __align__(16) char smem[];
  const int tt = threadIdx.x;
  const int wave = tt >> 6, lane = tt & 63;
  const int wm = wave >> 2, wn = wave & 3;
  const int nbm = M >> 8;
  // bijective XCD swizzle (grid % 8 == 0), n-major within XCD chunk
  const int cpx = (int)gridDim.x >> 3;
  const int wgid = ((int)blockIdx.x & 7) * cpx + ((int)blockIdx.x >> 3);
  const int m0 = (wgid % nbm) << 8;
  const int n0 = (wgid / nbm) << 8;
  const int l15 = lane & 15, lq = lane >> 4;

  // read-side swizzled K-granule (16B units within a 64B row): lq ^ (row&3),
  // row&3 == l15&3 for all frag rows (wm*128, wn*64, mf*16, nf*16 = 0 mod 4)
  const int swz = ((lq ^ (l15 & 3)) << 4);

  // staging: thread u covers LDS bytes u*16 (+8192 for second row-half) of
  // each 16 KiB panel; row = u>>2 (+128), granule = u&3; global source
  // granule pre-swizzled: (u&3) ^ (row&3)
  const int srow = tt >> 2;
  const int sg = (tt & 3) ^ (srow & 3);
  const bf16_t* pA0 = A  + (size_t)(m0 + srow) * K + sg * 8;
  const bf16_t* pA1 = pA0 + (size_t)128 * K;
  const bf16_t* pB0 = Bw + (size_t)(n0 + srow) * K + sg * 8;
  const bf16_t* pB1 = pB0 + (size_t)128 * K;

  f32x4 acc[8][4] = {};
  const int T = K >> 5;

  auto stage = [&](int tp) {
    int tw = tp; if (tw >= T) tw -= T;     // phantom wrap near tail
    const int kt = tw << 5;
    char* bb = smem + (size_t)(tp & 3) * 32768 + wave * 1024;
    gl2lds16(pA0 + kt, bb);
    gl2lds16(pA1 + kt, bb + 8192);
    gl2lds16(pB0 + kt, bb + 16384);
    gl2lds16(pB1 + kt, bb + 24576);
  };

  stage(0); stage(1); stage(2);            // 12 outstanding

  for (int t = 0; t < T; t++) {
    // gate: wait tile t's 4 loads (3-tile lead); leave 8 newer in flight
    asm volatile("s_waitcnt vmcnt(8)" ::: "memory");
    __builtin_amdgcn_s_barrier();
    stage(t + 3);                          // into buf freed at this barrier
    const char* as = smem + (size_t)(t & 3) * 32768;
    const char* bs = as + 16384;

    bf16x8 bfr[4], af[8];
    #pragma unroll
    for (int nf = 0; nf < 4; nf++)
      bfr[nf] = *(const bf16x8*)(bs + (wn * 64 + nf * 16 + l15) * 64 + swz);
    #pragma unroll
    for (int mf = 0; mf < 8; mf++)
      af[mf] = *(const bf16x8*)(as + (wm * 128 + mf * 16 + l15) * 64 + swz);

    __builtin_amdgcn_s_setprio(1);
    #pragma unroll
    for (int mf = 0; mf < 8; mf++)
      #pragma unroll
      for (int nf = 0; nf < 4; nf++)
        acc[mf][nf] = MFMA16(af[mf], bfr[nf], acc[mf][nf]);
    __builtin_amdgcn_s_setprio(0);
  }
  asm volatile("s_waitcnt vmcnt(0)" ::: "memory");  // drain phantoms

  const int er = lq * 4;
  if (MODE == 0) {
    const int seg = n0 >> 11;
    const int gc = (n0 & 2047) + wn * 64 + l15;
    #pragma unroll
    for (int mf = 0; mf < 8; mf++)
      #pragma unroll
      for (int nf = 0; nf < 4; nf++) {
        const int gr = m0 + wm * 128 + mf * 16 + er;
        #pragma unroll
        for (int jj = 0; jj < 4; jj++) {
          const size_t off = (size_t)(gr + jj) * 2048 + gc + nf * 16;
          const float v = acc[mf][nf][jj];
          if (seg == 0) {
            oq[off] = (bf16_t)(1.0f / (1.0f + expf(-v)));
          } else if (seg == 1) {
            okk[off] = (bf16_t)(1.0f / (1.0f + expf(v)));
            og[off] = fminf(v, 0.0f) - log1pf(expf(-fabsf(v)));
          } else {
            ov[off] = (bf16_t)v;
          }
        }
      }
  } else {
    const int gc = n0 + wn * 64 + l15;
    #pragma unroll
    for (int mf = 0; mf < 8; mf++)
      #pragma unroll
      for (int nf = 0; nf < 4; nf++) {
        const int gr = m0 + wm * 128 + mf * 16 + er;
        #pragma unroll
        for (int jj = 0; jj < 4; jj++)
          of[(size_t)(gr + jj) * N + gc + nf * 16] = acc[mf][nf][jj];
      }
  }
}

// ---------------------------------------------------------------------------
__global__ void f2b_kernel(const float* __restrict__ in, bf16_t* __restrict__ out, int n8)
{
  const int idx = blockIdx.x * 256 + threadIdx.x;
  if (idx >= n8) return;
  const float4 a = *(const float4*)(in + (size_t)idx * 8);
  const float4 b = *(const float4*)(in + (size_t)idx * 8 + 4);
  bf16x8 o;
  o[0] = (bf16_t)a.x; o[1] = (bf16_t)a.y; o[2] = (bf16_t)a.z; o[3] = (bf16_t)a.w;
  o[4] = (bf16_t)b.x; o[5] = (bf16_t)b.y; o[6] = (bf16_t)b.z; o[7] = (bf16_t)b.w;
  *(bf16x8*)(out + (size_t)idx * 8) = o;
}

// ---------------------------------------------------------------------------
// prep2: per (b,h,c): gc = cumsum(g); IN-PLACE q <- q*e^(gc-gl/2),
// k <- k*e^(gl/2-gc); eglh[blk][d] = e^(gl_d/2).  (mid-point gauge)
// ---------------------------------------------------------------------------
__global__ __launch_bounds__(256)
void prep2_kernel(bf16_t* __restrict__ qb, bf16_t* __restrict__ kb,
                  const float* __restrict__ g32, float* __restrict__ eglh)
{
  __shared__ __align__(16) float gs[64][132];
  __shared__ float gls[128];
  const int blk = blockIdx.x;
  const int c = blk & 31, h = (blk >> 5) & 15, b = blk >> 9;
  const size_t row0 = (size_t)b * 2048 + (size_t)c * 64;
  const int col0 = h * 128;
  const int tt = threadIdx.x;

  #pragma unroll
  for (int s = 0; s < 8; s++) {
    const int u = tt + s * 256;
    const int t = u >> 5, d4 = (u & 31) * 4;
    *(float4*)&gs[t][d4] = *(const float4*)(g32 + (row0 + t) * 2048 + col0 + d4);
  }
  __syncthreads();
  if (tt < 128) {
    float run = 0.0f;
    for (int t = 0; t < 64; t++) { run += gs[t][tt]; gs[t][tt] = run; }
    gls[tt] = 0.5f * run;
    eglh[(size_t)blk * 128 + tt] = expf(0.5f * run);
  }
  __syncthreads();
  #pragma unroll
  for (int s = 0; s < 4; s++) {
    const int u = tt + s * 256;
    const int t = u >> 4, d8 = (u & 15) * 8;
    bf16_t* qp = qb + (row0 + t) * 2048 + col0 + d8;
    bf16_t* kp = kb + (row0 + t) * 2048 + col0 + d8;
    const bf16x8 q8 = *(const bf16x8*)qp;
    const bf16x8 k8 = *(const bf16x8*)kp;
    bf16x8 qo, ko2;
    #pragma unroll
    for (int j = 0; j < 8; j++) {
      const float gc = gs[t][d8 + j];
      const float gh = gls[d8 + j];
      qo[j]  = (bf16_t)((float)q8[j] * expf(gc - gh));
      ko2[j] = (bf16_t)((float)k8[j] * expf(gh - gc));
    }
    *(bf16x8*)qp = qo;
    *(bf16x8*)kp = ko2;
  }
}

// ---------------------------------------------------------------------------
// state2: per (bh, e-half, d-half): sequential 32-chunk recurrence on a
// 64x64 quarter of T = S^T. Stores pre-update state scaled by e^(gl_c/2).
// ---------------------------------------------------------------------------
__global__ __launch_bounds__(256)
void state2_kernel(const bf16_t* __restrict__ kb, const bf16_t* __restrict__ vb,
                   const float* __restrict__ eglh, bf16_t* __restrict__ ST)
{
  __shared__ __align__(16) bf16_t kgt[64][72];
  __shared__ __align__(16) bf16_t vt[64][72];
  __shared__ float ehs[64];
  const int blk = blockIdx.x;                   // bh*4 + eh*2 + dh
  const int dh = blk & 1, eh = (blk >> 1) & 1, bh = blk >> 2;
  const int b = bh >> 4, h = bh & 15;
  const int col0 = h * 128;
  const int tt = threadIdx.x, wave = tt >> 6, lane = tt & 63;
  const int r = lane & 15, ko = (lane >> 4) * 8;
  const int d0 = dh * 64, e0 = eh * 64;
  f32x4 acc[4] = {};

  for (int c = 0; c < 32; c++) {
    const size_t cb = (size_t)bh * 32 + c;
    const size_t row0 = (size_t)b * 2048 + (size_t)c * 64;
    if (tt < 64) ehs[tt] = eglh[cb * 128 + d0 + tt];
    __syncthreads();
    #pragma unroll
    for (int s = 0; s < 2; s++) {
      const int u = tt + s * 256;
      const int t = u >> 3, d8 = (u & 7) * 8;
      const bf16x8 kv = *(const bf16x8*)(kb + (row0 + t) * 2048 + col0 + d0 + d8);
      const bf16x8 vv = *(const bf16x8*)(vb + (row0 + t) * 2048 + col0 + e0 + d8);
      #pragma unroll
      for (int j = 0; j < 8; j++) {
        kgt[d8 + j][t] = (bf16_t)((float)kv[j] * ehs[d8 + j]);
        vt[d8 + j][t]  = vv[j];
      }
    }
    __syncthreads();
    #pragma unroll
    for (int nf = 0; nf < 4; nf++) {
      const int d = nf * 16 + r;
      const float sd = ehs[d];
      #pragma unroll
      for (int jj = 0; jj < 4; jj++) {
        const int e = e0 + wave * 16 + (lane >> 4) * 4 + jj;
        ST[(cb * 128 + e) * 128 + d0 + d] = (bf16_t)(acc[nf][jj] * sd);
      }
    }
    #pragma unroll
    for (int nf = 0; nf < 4; nf++) {
      const float ev = ehs[nf * 16 + r];
      const float e2 = ev * ev;
      #pragma unroll
      for (int jj = 0; jj < 4; jj++) acc[nf][jj] *= e2;
    }
    #pragma unroll
    for (int ks = 0; ks < 2; ks++) {
      const bf16x8 a = *(const bf16x8*)&vt[wave * 16 + r][ks * 32 + ko];
      #pragma unroll
      for (int nf = 0; nf < 4; nf++) {
        const bf16x8 bfr = *(const bf16x8*)&kgt[nf * 16 + r][ks * 32 + ko];
        acc[nf] = MFMA16(a, bfr, acc[nf]);
      }
    }
    __syncthreads();
  }
}

// ---------------------------------------------------------------------------
// chunk2: per (b,h,c): A = qg2 @ kd2^T (tril) -> P ; o = P@v + qg2@ST'
// ---------------------------------------------------------------------------
__global__ __launch_bounds__(256)
void chunk2_kernel(const bf16_t* __restrict__ qb, const bf16_t* __restrict__ kb,
                   const bf16_t* __restrict__ vb, const bf16_t* __restrict__ ST,
                   bf16_t* __restrict__ o16)
{
  __shared__ __align__(16) bf16_t qgs[64][136];
  __shared__ __align__(16) bf16_t kds[64][136];
  __shared__ __align__(16) bf16_t vTs[128][72];
  __shared__ __align__(16) bf16_t Ps[64][72];
  const int blk = blockIdx.x;
  const int c = blk & 31, h = (blk >> 5) & 15, b = blk >> 9;
  const size_t row0 = (size_t)b * 2048 + (size_t)c * 64;
  const int col0 = h * 128;
  const int tt = threadIdx.x, wave = tt >> 6, lane = tt & 63;
  const int r = lane & 15, ko = (lane >> 4) * 8;

  #pragma unroll
  for (int s = 0; s < 4; s++) {
    const int u = tt + s * 256;
    const int t = u >> 4, d8 = (u & 15) * 8;
    *(bf16x8*)&qgs[t][d8] = *(const bf16x8*)(qb + (row0 + t) * 2048 + col0 + d8);
    *(bf16x8*)&kds[t][d8] = *(const bf16x8*)(kb + (row0 + t) * 2048 + col0 + d8);
  }
  #pragma unroll
  for (int s = 0; s < 4; s++) {
    const int u = tt + s * 256;
    const int t = u >> 4, e8 = (u & 15) * 8;
    const bf16x8 vv = *(const bf16x8*)(vb + (row0 + t) * 2048 + col0 + e8);
    #pragma unroll
    for (int j = 0; j < 8; j++) vTs[e8 + j][t] = vv[j];
  }
  __syncthreads();

  bf16x8 aq[4];
  #pragma unroll
  for (int ks = 0; ks < 4; ks++) aq[ks] = *(const bf16x8*)&qgs[wave * 16 + r][ks * 32 + ko];

  f32x4 accA[4] = {};
  #pragma unroll
  for (int ks = 0; ks < 4; ks++)
    #pragma unroll
    for (int sf = 0; sf < 4; sf++) {
      const bf16x8 bfr = *(const bf16x8*)&kds[sf * 16 + r][ks * 32 + ko];
      accA[sf] = MFMA16(aq[ks], bfr, accA[sf]);
    }

  #pragma unroll
  for (int sf = 0; sf < 4; sf++)
    #pragma unroll
    for (int jj = 0; jj < 4; jj++) {
      const int t = wave * 16 + (lane >> 4) * 4 + jj;
      const int s = sf * 16 + r;
      Ps[t][s] = (bf16_t)(t >= s ? accA[sf][jj] : 0.0f);
    }

  f32x4 acc[8] = {};
  const size_t stbase = (size_t)blk * 128 * 128;
  #pragma unroll
  for (int ks = 0; ks < 4; ks++)
    #pragma unroll
    for (int ne = 0; ne < 8; ne++) {
      const bf16x8 bfr = *(const bf16x8*)(ST + stbase + (size_t)(ne * 16 + r) * 128 + ks * 32 + ko);
      acc[ne] = MFMA16(aq[ks], bfr, acc[ne]);
    }
  #pragma unroll
  for (int ks = 0; ks < 2; ks++) {
    const bf16x8 pa = *(const bf16x8*)&Ps[wave * 16 + r][ks * 32 + ko];
    #pragma unroll
    for (int ne = 0; ne < 8; ne++) {
      const bf16x8 bfr = *(const bf16x8*)&vTs[ne * 16 + r][ks * 32 + ko];
      acc[ne] = MFMA16(pa, bfr, acc[ne]);
    }
  }

  #pragma unroll
  for (int ne = 0; ne < 8; ne++)
    #pragma unroll
    for (int jj = 0; jj < 4; jj++) {
      const int t = wave * 16 + (lane >> 4) * 4 + jj;
      const int e = ne * 16 + r;
      o16[(row0 + t) * 2048 + col0 + e] = (bf16_t)acc[ne][jj];
    }
}

// ---------------------------------------------------------------------------
// RMSNorm over D=2048, bf16 in -> bf16 out
// ---------------------------------------------------------------------------
__global__ __launch_bounds__(256)
void rmsb_kernel(const bf16_t* __restrict__ o16, const float* __restrict__ w,
                 bf16_t* __restrict__ ob)
{
  __shared__ float red[4];
  const size_t row = blockIdx.x;
  const int tt = threadIdx.x;
  const bf16x8 v = *(const bf16x8*)(o16 + row * 2048 + tt * 8);
  float f[8], ss = 0.0f;
  #pragma unroll
  for (int j = 0; j < 8; j++) { f[j] = (float)v[j]; ss += f[j] * f[j]; }
  #pragma unroll
  for (int off = 32; off > 0; off >>= 1) ss += __shfl_down(ss, off);
  if ((tt & 63) == 0) red[tt >> 6] = ss;
  __syncthreads();
  const float inv = rsqrtf((red[0] + red[1] + red[2] + red[3]) * (1.0f / 2048.0f) + 1e-5f);
  const float4 w0 = *(const float4*)(w + tt * 8);
  const float4 w1 = *(const float4*)(w + tt * 8 + 4);
  bf16x8 o;
  o[0] = (bf16_t)(f[0] * inv * w0.x); o[1] = (bf16_t)(f[1] * inv * w0.y);
  o[2] = (bf16_t)(f[2] * inv * w0.z); o[3] = (bf16_t)(f[3] * inv * w0.w);
  o[4] = (bf16_t)(f[4] * inv * w1.x); o[5] = (bf16_t)(f[5] * inv * w1.y);
  o[6] = (bf16_t)(f[6] * inv * w1.z); o[7] = (bf16_t)(f[7] * inv * w1.w);
  *(bf16x8*)(ob + row * 2048 + tt * 8) = o;
}

// ---------------------------------------------------------------------------
extern "C" void kernel_launch(void* const* d_in, const int* in_sizes, int n_in,
                              void* d_out, int out_size, void* d_ws, size_t ws_size,
                              hipStream_t stream)
{
  const float* x  = (const float*)d_in[0];
  const float* Wq = (const float*)d_in[1];
  const float* Wf = (const float*)d_in[2];
  const float* Wi = (const float*)d_in[3];
  const float* Wo = (const float*)d_in[4];
  const float* gw = (const float*)d_in[5];
  float* out = (float*)d_out;
  char* ws = (char*)d_ws;

  const int K = 2048;
  const size_t MB = 1ull << 20;
  const int LDS = 131072;

  (void)hipFuncSetAttribute((const void*)gemm256<0>,
      hipFuncAttributeMaxDynamicSharedMemorySize, LDS);
  (void)hipFuncSetAttribute((const void*)gemm256<1>,
      hipFuncAttributeMaxDynamicSharedMemorySize, LDS);

  auto run = [&](const float* xs, float* outs, int nbs) {
    const int Ms = nbs * 2048;
    const size_t Sx = (size_t)Ms * 2048 * 2;     // bf16 matrix bytes
    bf16_t* xb  = (bf16_t*)(ws + 0);
    bf16_t* qb  = (bf16_t*)(ws + Sx);
    bf16_t* kb  = (bf16_t*)(ws + 2 * Sx);
    bf16_t* vb  = (bf16_t*)(ws + 3 * Sx);
    float*  g32 = (float*) (ws + 4 * Sx);        // 2*Sx bytes
    bf16_t* Wb  = (bf16_t*)(ws + 6 * Sx);        // 24 MiB (QKV fused / Wo)
    float*  egh = (float*) (ws + 6 * Sx + 24 * MB);
    bf16_t* STp = (bf16_t*)(ws + 4 * Sx);        // alias g32 (dead after prep)
    bf16_t* o16 = (bf16_t*)(ws + 0);             // alias xb  (dead after QKV gemm)
    bf16_t* ob  = (bf16_t*)(ws + Sx);            // alias qb  (dead after chunk)

    const int n8x = Ms * 2048 / 8;
    const int n8w = 2048 * 2048 / 8;

    f2b_kernel<<<(n8x + 255) / 256, 256, 0, stream>>>(xs, xb, n8x);
    f2b_kernel<<<(n8w + 255) / 256, 256, 0, stream>>>(Wq, Wb, n8w);
    f2b_kernel<<<(n8w + 255) / 256, 256, 0, stream>>>(Wf, Wb + 4194304, n8w);
    f2b_kernel<<<(n8w + 255) / 256, 256, 0, stream>>>(Wi, Wb + 8388608, n8w);

    gemm256<0><<<(Ms / 256) * (6144 / 256), 512, LDS, stream>>>(
        xb, Wb, qb, kb, vb, g32, nullptr, Ms, 6144, K);

    prep2_kernel<<<nbs * 512, 256, 0, stream>>>(qb, kb, g32, egh);
    state2_kernel<<<nbs * 64, 256, 0, stream>>>(kb, vb, egh, STp);
    chunk2_kernel<<<nbs * 512, 256, 0, stream>>>(qb, kb, vb, STp, o16);
    rmsb_kernel<<<Ms, 256, 0, stream>>>(o16, gw, ob);

    f2b_kernel<<<(n8w + 255) / 256, 256, 0, stream>>>(Wo, Wb, n8w);
    gemm256<1><<<(Ms / 256) * (2048 / 256), 512, LDS, stream>>>(
        ob, Wb, nullptr, nullptr, nullptr, nullptr, outs, Ms, 2048, K);
  };

  const size_t Sx_full = (size_t)8192 * 2048 * 2;
  const size_t need_full = 6 * Sx_full + 24 * MB + 2048 * 128 * 4;
  if (ws_size >= need_full) {
    run(x, out, 4);
  } else {
    for (int sb = 0; sb < 4; sb++)
      run(x + (size_t)sb * 2048 * 2048, out + (size_t)sb * 2048 * 2048, 1);
  }

  (void)in_sizes; (void)n_in; (void)out_size;
}

// Round 9
// 601.660 us; speedup vs baseline: 1.8887x; 1.8887x over previous
//
#include <hip/hip_runtime.h>
#include <math.h>

typedef __bf16 bf16_t;
typedef __bf16 bf16x8 __attribute__((ext_vector_type(8)));
typedef float  f32x4  __attribute__((ext_vector_type(4)));

__device__ __forceinline__ void gl2lds16(const void* g, void* l) {
  __builtin_amdgcn_global_load_lds((__attribute__((address_space(1))) void*)g,
                                   (__attribute__((address_space(3))) void*)l,
                                   16, 0, 0);
}

#define MFMA16(a, b, c) __builtin_amdgcn_mfma_f32_16x16x32_bf16(a, b, c, 0, 0, 0)

// ---------------------------------------------------------------------------
// 128x128 tile, BK=64, 4 waves, 32 KiB LDS single-buffer, m97 2-barrier loop.
// High-occupancy regime (~3 blocks/CU): cross-block TLP hides stage drains
// (m114) -- wall-verified better than every 1-block/CU 256' variant (R4-R8).
// vs R2 baseline: BK 32->64 (half the tiles/barriers) and T2 swizzle with
// 128B rows -- granule slot = (khalf*4+lq) ^ (lane&7); each 8-lane b128
// processing group hits 8 distinct 16B slots (R4/R6/R7 measured 0 conflicts;
// R2's linear BK=32 layout had 8.4M).  Staging pre-swizzles the GLOBAL
// source column (LDS dest linear, m104 rule).
// C = A * B^T. MODE 0: fused QKV epilogue (seg = n0>>11: 0->q=sigmoid,
// 1->k=sigmoid(-v) + g=logsigmoid(v), 2->v). MODE 1: f32 passthrough out.
// ---------------------------------------------------------------------------
template<int MODE>
__global__ __launch_bounds__(256, 2)
void gemm_bt2(const bf16_t* __restrict__ A, const bf16_t* __restrict__ Bw,
              bf16_t* __restrict__ oq, bf16_t* __restrict__ okk,
              bf16_t* __restrict__ ov, float* __restrict__ og,
              float* __restrict__ of, int M, int N, int K)
{
  __shared__ __align__(16) bf16_t As[128 * 64];
  __shared__ __align__(16) bf16_t Bs[128 * 64];
  const int tt   = threadIdx.x;
  const int wave = tt >> 6;
  const int lane = tt & 63;
  const int nbn = N >> 7;
  const int m0 = (int)(blockIdx.x / nbn) << 7;
  const int n0 = (int)(blockIdx.x % nbn) << 7;
  const int wr = (wave >> 1) * 64;
  const int wc = (wave & 1) * 64;
  const int l15 = lane & 15, lq = lane >> 4;

  // read-side swizzled column byte offsets within a 128B row (k-halves 0/1)
  const int tk0 = (lq * 16) ^ ((lane & 7) << 4);
  const int tk1 = (64 + lq * 16) ^ ((lane & 7) << 4);

  // staging: wave base w*1024B (+i*4096B); lane covers row w*8+i*32+(l>>3),
  // LDS slot l&7 -> pre-swizzled global granule (l&7)^(l>>3)
  const int srow = wave * 8 + (lane >> 3);
  const int sg = (lane & 7) ^ (lane >> 3);
  const bf16_t* pA = A  + (size_t)(m0 + srow) * K + sg * 8;
  const bf16_t* pB = Bw + (size_t)(n0 + srow) * K + sg * 8;

  f32x4 acc[4][4] = {};

  for (int kt = 0; kt < K; kt += 64) {
    #pragma unroll
    for (int i = 0; i < 4; i++) {
      gl2lds16(pA + (size_t)i * 32 * K + kt, (void*)(As + wave * 512 + i * 2048));
      gl2lds16(pB + (size_t)i * 32 * K + kt, (void*)(Bs + wave * 512 + i * 2048));
    }
    asm volatile("s_waitcnt vmcnt(0)" ::: "memory");
    __syncthreads();

    bf16x8 a[2][4], b[2][4];
    #pragma unroll
    for (int mf = 0; mf < 4; mf++) {
      const char* rp = (const char*)As + (wr + mf * 16 + l15) * 128;
      a[0][mf] = *(const bf16x8*)(rp + tk0);
      a[1][mf] = *(const bf16x8*)(rp + tk1);
    }
    #pragma unroll
    for (int nf = 0; nf < 4; nf++) {
      const char* rp = (const char*)Bs + (wc + nf * 16 + l15) * 128;
      b[0][nf] = *(const bf16x8*)(rp + tk0);
      b[1][nf] = *(const bf16x8*)(rp + tk1);
    }
    #pragma unroll
    for (int kh = 0; kh < 2; kh++)
      #pragma unroll
      for (int mf = 0; mf < 4; mf++)
        #pragma unroll
        for (int nf = 0; nf < 4; nf++)
          acc[mf][nf] = MFMA16(a[kh][mf], b[kh][nf], acc[mf][nf]);
    __syncthreads();
  }

  const int er = lq * 4;
  if (MODE == 0) {
    const int seg = n0 >> 11;
    const int gc = (n0 & 2047) + wc;
    #pragma unroll
    for (int mf = 0; mf < 4; mf++)
      #pragma unroll
      for (int nf = 0; nf < 4; nf++) {
        const int gr = m0 + wr + mf * 16 + er;
        #pragma unroll
        for (int jj = 0; jj < 4; jj++) {
          const size_t off = (size_t)(gr + jj) * 2048 + gc + nf * 16 + l15;
          const float v = acc[mf][nf][jj];
          if (seg == 0) {
            oq[off] = (bf16_t)(1.0f / (1.0f + expf(-v)));
          } else if (seg == 1) {
            okk[off] = (bf16_t)(1.0f / (1.0f + expf(v)));
            og[off] = fminf(v, 0.0f) - log1pf(expf(-fabsf(v)));
          } else {
            ov[off] = (bf16_t)v;
          }
        }
      }
  } else {
    const int gc = n0 + wc + l15;
    #pragma unroll
    for (int mf = 0; mf < 4; mf++)
      #pragma unroll
      for (int nf = 0; nf < 4; nf++) {
        const int gr = m0 + wr + mf * 16 + er;
        #pragma unroll
        for (int jj = 0; jj < 4; jj++)
          of[(size_t)(gr + jj) * N + gc + nf * 16] = acc[mf][nf][jj];
      }
  }
}

// ---------------------------------------------------------------------------
__global__ void f2b_kernel(const float* __restrict__ in, bf16_t* __restrict__ out, int n8)
{
  const int idx = blockIdx.x * 256 + threadIdx.x;
  if (idx >= n8) return;
  const float4 a = *(const float4*)(in + (size_t)idx * 8);
  const float4 b = *(const float4*)(in + (size_t)idx * 8 + 4);
  bf16x8 o;
  o[0] = (bf16_t)a.x; o[1] = (bf16_t)a.y; o[2] = (bf16_t)a.z; o[3] = (bf16_t)a.w;
  o[4] = (bf16_t)b.x; o[5] = (bf16_t)b.y; o[6] = (bf16_t)b.z; o[7] = (bf16_t)b.w;
  *(bf16x8*)(out + (size_t)idx * 8) = o;
}

// ---------------------------------------------------------------------------
// prep2: per (b,h,c): gc = cumsum(g); IN-PLACE q <- q*e^(gc-gl/2),
// k <- k*e^(gl/2-gc); eglh[blk][d] = e^(gl_d/2).  (mid-point gauge)
// ---------------------------------------------------------------------------
__global__ __launch_bounds__(256)
void prep2_kernel(bf16_t* __restrict__ qb, bf16_t* __restrict__ kb,
                  const float* __restrict__ g32, float* __restrict__ eglh)
{
  __shared__ __align__(16) float gs[64][132];
  __shared__ float gls[128];
  const int blk = blockIdx.x;
  const int c = blk & 31, h = (blk >> 5) & 15, b = blk >> 9;
  const size_t row0 = (size_t)b * 2048 + (size_t)c * 64;
  const int col0 = h * 128;
  const int tt = threadIdx.x;

  #pragma unroll
  for (int s = 0; s < 8; s++) {
    const int u = tt + s * 256;
    const int t = u >> 5, d4 = (u & 31) * 4;
    *(float4*)&gs[t][d4] = *(const float4*)(g32 + (row0 + t) * 2048 + col0 + d4);
  }
  __syncthreads();
  if (tt < 128) {
    float run = 0.0f;
    for (int t = 0; t < 64; t++) { run += gs[t][tt]; gs[t][tt] = run; }
    gls[tt] = 0.5f * run;
    eglh[(size_t)blk * 128 + tt] = expf(0.5f * run);
  }
  __syncthreads();
  #pragma unroll
  for (int s = 0; s < 4; s++) {
    const int u = tt + s * 256;
    const int t = u >> 4, d8 = (u & 15) * 8;
    bf16_t* qp = qb + (row0 + t) * 2048 + col0 + d8;
    bf16_t* kp = kb + (row0 + t) * 2048 + col0 + d8;
    const bf16x8 q8 = *(const bf16x8*)qp;
    const bf16x8 k8 = *(const bf16x8*)kp;
    bf16x8 qo, ko2;
    #pragma unroll
    for (int j = 0; j < 8; j++) {
      const float gc = gs[t][d8 + j];
      const float gh = gls[d8 + j];
      qo[j]  = (bf16_t)((float)q8[j] * expf(gc - gh));
      ko2[j] = (bf16_t)((float)k8[j] * expf(gh - gc));
    }
    *(bf16x8*)qp = qo;
    *(bf16x8*)kp = ko2;
  }
}

// ---------------------------------------------------------------------------
// state2: per (bh, e-half, d-half): sequential 32-chunk recurrence on a
// 64x64 quarter of T = S^T. Stores pre-update state scaled by e^(gl_c/2).
// ---------------------------------------------------------------------------
__global__ __launch_bounds__(256)
void state2_kernel(const bf16_t* __restrict__ kb, const bf16_t* __restrict__ vb,
                   const float* __restrict__ eglh, bf16_t* __restrict__ ST)
{
  __shared__ __align__(16) bf16_t kgt[64][72];
  __shared__ __align__(16) bf16_t vt[64][72];
  __shared__ float ehs[64];
  const int blk = blockIdx.x;                   // bh*4 + eh*2 + dh
  const int dh = blk & 1, eh = (blk >> 1) & 1, bh = blk >> 2;
  const int b = bh >> 4, h = bh & 15;
  const int col0 = h * 128;
  const int tt = threadIdx.x, wave = tt >> 6, lane = tt & 63;
  const int r = lane & 15, ko = (lane >> 4) * 8;
  const int d0 = dh * 64, e0 = eh * 64;
  f32x4 acc[4] = {};

  for (int c = 0; c < 32; c++) {
    const size_t cb = (size_t)bh * 32 + c;
    const size_t row0 = (size_t)b * 2048 + (size_t)c * 64;
    if (tt < 64) ehs[tt] = eglh[cb * 128 + d0 + tt];
    __syncthreads();
    #pragma unroll
    for (int s = 0; s < 2; s++) {
      const int u = tt + s * 256;
      const int t = u >> 3, d8 = (u & 7) * 8;
      const bf16x8 kv = *(const bf16x8*)(kb + (row0 + t) * 2048 + col0 + d0 + d8);
      const bf16x8 vv = *(const bf16x8*)(vb + (row0 + t) * 2048 + col0 + e0 + d8);
      #pragma unroll
      for (int j = 0; j < 8; j++) {
        kgt[d8 + j][t] = (bf16_t)((float)kv[j] * ehs[d8 + j]);
        vt[d8 + j][t]  = vv[j];
      }
    }
    __syncthreads();
    #pragma unroll
    for (int nf = 0; nf < 4; nf++) {
      const int d = nf * 16 + r;
      const float sd = ehs[d];
      #pragma unroll
      for (int jj = 0; jj < 4; jj++) {
        const int e = e0 + wave * 16 + (lane >> 4) * 4 + jj;
        ST[(cb * 128 + e) * 128 + d0 + d] = (bf16_t)(acc[nf][jj] * sd);
      }
    }
    #pragma unroll
    for (int nf = 0; nf < 4; nf++) {
      const float ev = ehs[nf * 16 + r];
      const float e2 = ev * ev;
      #pragma unroll
      for (int jj = 0; jj < 4; jj++) acc[nf][jj] *= e2;
    }
    #pragma unroll
    for (int ks = 0; ks < 2; ks++) {
      const bf16x8 a = *(const bf16x8*)&vt[wave * 16 + r][ks * 32 + ko];
      #pragma unroll
      for (int nf = 0; nf < 4; nf++) {
        const bf16x8 bfr = *(const bf16x8*)&kgt[nf * 16 + r][ks * 32 + ko];
        acc[nf] = MFMA16(a, bfr, acc[nf]);
      }
    }
    __syncthreads();
  }
}

// ---------------------------------------------------------------------------
// chunk2: per (b,h,c): A = qg2 @ kd2^T (tril) -> P ; o = P@v + qg2@ST'
// ---------------------------------------------------------------------------
__global__ __launch_bounds__(256)
void chunk2_kernel(const bf16_t* __restrict__ qb, const bf16_t* __restrict__ kb,
                   const bf16_t* __restrict__ vb, const bf16_t* __restrict__ ST,
                   bf16_t* __restrict__ o16)
{
  __shared__ __align__(16) bf16_t qgs[64][136];
  __shared__ __align__(16) bf16_t kds[64][136];
  __shared__ __align__(16) bf16_t vTs[128][72];
  __shared__ __align__(16) bf16_t Ps[64][72];
  const int blk = blockIdx.x;
  const int c = blk & 31, h = (blk >> 5) & 15, b = blk >> 9;
  const size_t row0 = (size_t)b * 2048 + (size_t)c * 64;
  const int col0 = h * 128;
  const int tt = threadIdx.x, wave = tt >> 6, lane = tt & 63;
  const int r = lane & 15, ko = (lane >> 4) * 8;

  #pragma unroll
  for (int s = 0; s < 4; s++) {
    const int u = tt + s * 256;
    const int t = u >> 4, d8 = (u & 15) * 8;
    *(bf16x8*)&qgs[t][d8] = *(const bf16x8*)(qb + (row0 + t) * 2048 + col0 + d8);
    *(bf16x8*)&kds[t][d8] = *(const bf16x8*)(kb + (row0 + t) * 2048 + col0 + d8);
  }
  #pragma unroll
  for (int s = 0; s < 4; s++) {
    const int u = tt + s * 256;
    const int t = u >> 4, e8 = (u & 15) * 8;
    const bf16x8 vv = *(const bf16x8*)(vb + (row0 + t) * 2048 + col0 + e8);
    #pragma unroll
    for (int j = 0; j < 8; j++) vTs[e8 + j][t] = vv[j];
  }
  __syncthreads();

  bf16x8 aq[4];
  #pragma unroll
  for (int ks = 0; ks < 4; ks++) aq[ks] = *(const bf16x8*)&qgs[wave * 16 + r][ks * 32 + ko];

  f32x4 accA[4] = {};
  #pragma unroll
  for (int ks = 0; ks < 4; ks++)
    #pragma unroll
    for (int sf = 0; sf < 4; sf++) {
      const bf16x8 bfr = *(const bf16x8*)&kds[sf * 16 + r][ks * 32 + ko];
      accA[sf] = MFMA16(aq[ks], bfr, accA[sf]);
    }

  #pragma unroll
  for (int sf = 0; sf < 4; sf++)
    #pragma unroll
    for (int jj = 0; jj < 4; jj++) {
      const int t = wave * 16 + (lane >> 4) * 4 + jj;
      const int s = sf * 16 + r;
      Ps[t][s] = (bf16_t)(t >= s ? accA[sf][jj] : 0.0f);
    }

  f32x4 acc[8] = {};
  const size_t stbase = (size_t)blk * 128 * 128;
  #pragma unroll
  for (int ks = 0; ks < 4; ks++)
    #pragma unroll
    for (int ne = 0; ne < 8; ne++) {
      const bf16x8 bfr = *(const bf16x8*)(ST + stbase + (size_t)(ne * 16 + r) * 128 + ks * 32 + ko);
      acc[ne] = MFMA16(aq[ks], bfr, acc[ne]);
    }
  #pragma unroll
  for (int ks = 0; ks < 2; ks++) {
    const bf16x8 pa = *(const bf16x8*)&Ps[wave * 16 + r][ks * 32 + ko];
    #pragma unroll
    for (int ne = 0; ne < 8; ne++) {
      const bf16x8 bfr = *(const bf16x8*)&vTs[ne * 16 + r][ks * 32 + ko];
      acc[ne] = MFMA16(pa, bfr, acc[ne]);
    }
  }

  #pragma unroll
  for (int ne = 0; ne < 8; ne++)
    #pragma unroll
    for (int jj = 0; jj < 4; jj++) {
      const int t = wave * 16 + (lane >> 4) * 4 + jj;
      const int e = ne * 16 + r;
      o16[(row0 + t) * 2048 + col0 + e] = (bf16_t)acc[ne][jj];
    }
}

// ---------------------------------------------------------------------------
// RMSNorm over D=2048, bf16 in -> bf16 out
// ---------------------------------------------------------------------------
__global__ __launch_bounds__(256)
void rmsb_kernel(const bf16_t* __restrict__ o16, const float* __restrict__ w,
                 bf16_t* __restrict__ ob)
{
  __shared__ float red[4];
  const size_t row = blockIdx.x;
  const int tt = threadIdx.x;
  const bf16x8 v = *(const bf16x8*)(o16 + row * 2048 + tt * 8);
  float f[8], ss = 0.0f;
  #pragma unroll
  for (int j = 0; j < 8; j++) { f[j] = (float)v[j]; ss += f[j] * f[j]; }
  #pragma unroll
  for (int off = 32; off > 0; off >>= 1) ss += __shfl_down(ss, off);
  if ((tt & 63) == 0) red[tt >> 6] = ss;
  __syncthreads();
  const float inv = rsqrtf((red[0] + red[1] + red[2] + red[3]) * (1.0f / 2048.0f) + 1e-5f);
  const float4 w0 = *(const float4*)(w + tt * 8);
  const float4 w1 = *(const float4*)(w + tt * 8 + 4);
  bf16x8 o;
  o[0] = (bf16_t)(f[0] * inv * w0.x); o[1] = (bf16_t)(f[1] * inv * w0.y);
  o[2] = (bf16_t)(f[2] * inv * w0.z); o[3] = (bf16_t)(f[3] * inv * w0.w);
  o[4] = (bf16_t)(f[4] * inv * w1.x); o[5] = (bf16_t)(f[5] * inv * w1.y);
  o[6] = (bf16_t)(f[6] * inv * w1.z); o[7] = (bf16_t)(f[7] * inv * w1.w);
  *(bf16x8*)(ob + row * 2048 + tt * 8) = o;
}

// ---------------------------------------------------------------------------
extern "C" void kernel_launch(void* const* d_in, const int* in_sizes, int n_in,
                              void* d_out, int out_size, void* d_ws, size_t ws_size,
                              hipStream_t stream)
{
  const float* x  = (const float*)d_in[0];
  const float* Wq = (const float*)d_in[1];
  const float* Wf = (const float*)d_in[2];
  const float* Wi = (const float*)d_in[3];
  const float* Wo = (const float*)d_in[4];
  const float* gw = (const float*)d_in[5];
  float* out = (float*)d_out;
  char* ws = (char*)d_ws;

  const int K = 2048;
  const size_t MB = 1ull << 20;

  auto run = [&](const float* xs, float* outs, int nbs) {
    const int Ms = nbs * 2048;
    const size_t Sx = (size_t)Ms * 2048 * 2;     // bf16 matrix bytes
    bf16_t* xb  = (bf16_t*)(ws + 0);
    bf16_t* qb  = (bf16_t*)(ws + Sx);
    bf16_t* kb  = (bf16_t*)(ws + 2 * Sx);
    bf16_t* vb  = (bf16_t*)(ws + 3 * Sx);
    float*  g32 = (float*) (ws + 4 * Sx);        // 2*Sx bytes
    bf16_t* Wb  = (bf16_t*)(ws + 6 * Sx);        // 24 MiB (QKV fused / Wo)
    float*  egh = (float*) (ws + 6 * Sx + 24 * MB);
    bf16_t* STp = (bf16_t*)(ws + 4 * Sx);        // alias g32 (dead after prep)
    bf16_t* o16 = (bf16_t*)(ws + 0);             // alias xb  (dead after QKV gemm)
    bf16_t* ob  = (bf16_t*)(ws + Sx);            // alias qb  (dead after chunk)

    const int n8x = Ms * 2048 / 8;
    const int n8w = 2048 * 2048 / 8;

    f2b_kernel<<<(n8x + 255) / 256, 256, 0, stream>>>(xs, xb, n8x);
    f2b_kernel<<<(n8w + 255) / 256, 256, 0, stream>>>(Wq, Wb, n8w);
    f2b_kernel<<<(n8w + 255) / 256, 256, 0, stream>>>(Wf, Wb + 4194304, n8w);
    f2b_kernel<<<(n8w + 255) / 256, 256, 0, stream>>>(Wi, Wb + 8388608, n8w);

    gemm_bt2<0><<<(Ms / 128) * (6144 / 128), 256, 0, stream>>>(
        xb, Wb, qb, kb, vb, g32, nullptr, Ms, 6144, K);

    prep2_kernel<<<nbs * 512, 256, 0, stream>>>(qb, kb, g32, egh);
    state2_kernel<<<nbs * 64, 256, 0, stream>>>(kb, vb, egh, STp);
    chunk2_kernel<<<nbs * 512, 256, 0, stream>>>(qb, kb, vb, STp, o16);
    rmsb_kernel<<<Ms, 256, 0, stream>>>(o16, gw, ob);

    f2b_kernel<<<(n8w + 255) / 256, 256, 0, stream>>>(Wo, Wb, n8w);
    gemm_bt2<1><<<(Ms / 128) * (2048 / 128), 256, 0, stream>>>(
        ob, Wb, nullptr, nullptr, nullptr, nullptr, out ? outs : outs, Ms, 2048, K);
  };

  const size_t Sx_full = (size_t)8192 * 2048 * 2;
  const size_t need_full = 6 * Sx_full + 24 * MB + 2048 * 128 * 4;
  if (ws_size >= need_full) {
    run(x, out, 4);
  } else {
    for (int sb = 0; sb < 4; sb++)
      run(x + (size_t)sb * 2048 * 2048, out + (size_t)sb * 2048 * 2048, 1);
  }

  (void)in_sizes; (void)n_in; (void)out_size;
}